// Round 8
// baseline (296.112 us; speedup 1.0000x reference)
//
#include <hip/hip_runtime.h>

typedef __bf16 bf16;
typedef bf16 bf16x8 __attribute__((ext_vector_type(8)));
typedef bf16 bf16x4 __attribute__((ext_vector_type(4)));
typedef float f32x4 __attribute__((ext_vector_type(4)));
typedef float f32x8 __attribute__((ext_vector_type(8)));
typedef float f32x16 __attribute__((ext_vector_type(16)));
typedef unsigned int u32;

#define BB 8
#define NN 2048
#define MM 4096

// async global->LDS: each lane moves 16B to (wave-uniform base + lane*16)
__device__ __forceinline__ void gload16(const void* g, void* l) {
  __builtin_amdgcn_global_load_lds(
      (const u32 __attribute__((address_space(1)))*)g,
      (u32 __attribute__((address_space(3)))*)l, 16, 0, 0);
}

// ---------------------------------------------------------------------------
// Weight prep: W[k][n] f32 -> Wt[n][k] bf16  (4 matrices in one launch)
// ---------------------------------------------------------------------------
__global__ __launch_bounds__(256) void prep_wt(
    const float* W0, const float* W1, const float* W2, const float* W3,
    bf16* T0, bf16* T1, bf16* T2, bf16* T3) {
  const float* W; bf16* T;
  switch (blockIdx.y) {
    case 0:  W = W0; T = T0; break;
    case 1:  W = W1; T = T1; break;
    case 2:  W = W2; T = T2; break;
    default: W = W3; T = T3; break;
  }
  int n = blockIdx.x, k = threadIdx.x;
  T[n * 256 + k] = (bf16)W[k * 256 + n];
}

// ---------------------------------------------------------------------------
// GEMM: C = (A[R][256] @ W + bias) * scale, W as Wt[n][k] bf16.
// AM: 0 = A f32 flat [R][256]; 1 = A bf16 head-split [b*4+h][2048][64]
// CM: 0 = C f32 flat; 1 = C bf16 head-split;
//     4 = fused K/V image write via LDS-staged coalesced epilogue
// ---------------------------------------------------------------------------
template<int AM, int CM>
__global__ __launch_bounds__(256) void gemm_bias(
    const void* Aptr, const bf16* Wt, const float* bias, const float* bias2,
    void* Cout, float scale) {
  __shared__ __align__(16) char smem[32768];
  bf16* As = (bf16*)smem;
  bf16* Bs = (bf16*)(smem + 16384);
  const int t = threadIdx.x;
  const int lane = t & 63, wid = t >> 6;
  const int l15 = lane & 15, lhi = lane >> 4, l7 = lane & 7;
  const int row0 = blockIdx.x * 128, col0 = blockIdx.y * 128;
  const int wm = (wid >> 1) * 64, wn = (wid & 1) * 64;

  f32x4 zero4 = {0.f, 0.f, 0.f, 0.f};
  f32x4 acc[4][4];
#pragma unroll
  for (int i = 0; i < 4; ++i)
#pragma unroll
    for (int j = 0; j < 4; ++j) acc[i][j] = zero4;

  for (int k0 = 0; k0 < 256; k0 += 64) {
    __syncthreads();
    if (AM == 0) {
      const float* Af = (const float*)Aptr;
#pragma unroll
      for (int i = 0; i < 8; ++i) {
        int idx = t + i * 256;
        int m = idx >> 4, c4 = idx & 15;
        f32x4 v = *(const f32x4*)(Af + (size_t)(row0 + m) * 256 + k0 + c4 * 4);
        bf16x4 bv;
#pragma unroll
        for (int j = 0; j < 4; ++j) bv[j] = (bf16)v[j];
        *(bf16x4*)((char*)As + m * 128 + ((c4 * 8) ^ ((m & 7) << 4))) = bv;
      }
    } else {
      const bf16* Ab = (const bf16*)Aptr;
#pragma unroll
      for (int i = 0; i < 4; ++i) {
        int idx = t + i * 256;
        int m = idx >> 3, c = idx & 7;
        int r = row0 + m;
        int b = r >> 11, nl = r & 2047, h = k0 >> 6;
        const bf16* src = Ab + ((size_t)(b * 4 + h) * 2048 + nl) * 64 + c * 8;
        bf16x8 v = *(const bf16x8*)src;
        *(bf16x8*)((char*)As + m * 128 + ((c * 16) ^ ((m & 7) << 4))) = v;
      }
    }
#pragma unroll
    for (int i = 0; i < 4; ++i) {
      int idx = t + i * 256;
      int n = idx >> 3, c = idx & 7;
      bf16x8 v = *(const bf16x8*)(Wt + (size_t)(col0 + n) * 256 + k0 + c * 8);
      *(bf16x8*)((char*)Bs + n * 128 + ((c * 16) ^ ((n & 7) << 4))) = v;
    }
    __syncthreads();
#pragma unroll
    for (int kh = 0; kh < 2; ++kh) {
      bf16x8 a[4], b[4];
#pragma unroll
      for (int mi = 0; mi < 4; ++mi) {
        int row = wm + mi * 16 + l15;
        a[mi] = *(const bf16x8*)((char*)As + row * 128 + ((kh * 64 + lhi * 16) ^ (l7 << 4)));
      }
#pragma unroll
      for (int ni = 0; ni < 4; ++ni) {
        int row = wn + ni * 16 + l15;
        b[ni] = *(const bf16x8*)((char*)Bs + row * 128 + ((kh * 64 + lhi * 16) ^ (l7 << 4)));
      }
#pragma unroll
      for (int mi = 0; mi < 4; ++mi)
#pragma unroll
        for (int ni = 0; ni < 4; ++ni)
          acc[mi][ni] = __builtin_amdgcn_mfma_f32_16x16x32_bf16(a[mi], b[ni], acc[mi][ni], 0, 0, 0);
    }
  }

  if (CM == 4) __syncthreads();   // done with As/Bs; reuse smem as image stage

#pragma unroll
  for (int mi = 0; mi < 4; ++mi)
#pragma unroll
    for (int ni = 0; ni < 4; ++ni) {
      int n = col0 + wn + ni * 16 + l15;
      float bvv = (CM == 4) ? (n < 256 ? bias[n] : bias2[n - 256]) : bias[n];
#pragma unroll
      for (int r = 0; r < 4; ++r) {
        int mrow = row0 + wm + mi * 16 + lhi * 4 + r;
        float val = (acc[mi][ni][r] + bvv) * scale;
        if (CM == 0) {
          ((float*)Cout)[(size_t)mrow * 256 + n] = val;
        } else if (CM == 1) {
          int b = mrow >> 11, nl = mrow & 2047;
          ((bf16*)Cout)[((size_t)(b * 4 + (n >> 6)) * 2048 + nl) * 64 + (n & 63)] = (bf16)val;
        } else {
          // CM==4: write exact image bytes into LDS (coalesced copy after)
          int dm = wm + mi * 16 + lhi * 4 + r;     // 0..127
          int dn = wn + ni * 16 + l15;             // 0..127
          int dkt = dm >> 6, kvl = dm & 63;
          int dh = dn >> 6, d = dn & 63;
          int inner;
          if (col0 < 256)  // K image: [kv>>5][d>>3][kv&31][d&7]
            inner = (((kvl >> 5) & 1) << 12) + ((d >> 3) << 9)
                  + ((kvl & 31) << 4) + ((d & 7) << 1);
          else             // V image: [d>>5][(kv>>3)&7][(kv>>2)&1][d&31][kv&3]
            inner = ((d >> 5) << 12) + (((kvl >> 3) & 7) << 9)
                  + (((kvl >> 2) & 1) << 8) + ((d & 31) << 3) + ((kvl & 3) << 1);
          *(bf16*)(smem + (dkt * 2 + dh) * 8192 + inner) = (bf16)val;
        }
      }
    }

  if (CM == 4) {
    __syncthreads();
    const int isK = (col0 < 256);
    int b = row0 >> 12, kt0 = (row0 & 4095) >> 6, h0 = (col0 & 255) >> 6;
#pragma unroll
    for (int c = 0; c < 4; ++c) {
      int dkt = c >> 1, dh = c & 1;
      char* dst = (char*)Cout + ((size_t)((b * 4 + h0 + dh) * 64 + kt0 + dkt)) * 16384
                  + (isK ? 0 : 8192);
      *(bf16x8*)(dst + t * 16)        = *(const bf16x8*)(smem + c * 8192 + t * 16);
      *(bf16x8*)(dst + 4096 + t * 16) = *(const bf16x8*)(smem + c * 8192 + 4096 + t * 16);
    }
  }
}

// ---------------------------------------------------------------------------
// Flash cross-attention, swapped-operand, LDS-image K/V tiles, kv-split x2.
// Block = 128 q x (b,h), 8 waves: wave w -> q-tile (w>>1), kv-half (w&1).
// Fixed-max softmax (exp2 domain). Staging via global_load_lds (async DMA).
// PV accumulators split into 4 independent chains (dep-latency relief).
// ---------------------------------------------------------------------------
__device__ __forceinline__ u32 pkbf(float a, float b) {
  union { bf16 h[2]; u32 u; } p;
  p.h[0] = (bf16)a; p.h[1] = (bf16)b;
  return p.u;
}

#if defined(__has_builtin)
#if __has_builtin(__builtin_amdgcn_mfma_f32_32x32x8bf16_1k)
#define HAVE_MFMA8 1
#endif
#endif

#ifdef HAVE_MFMA8
typedef short s16x4 __attribute__((ext_vector_type(4)));
__device__ __forceinline__ f32x16 mfma8(bf16x4 a, u32 b0, u32 b1, f32x16 c) {
  union { bf16x4 h; s16x4 s; } au; au.h = a;
  union { u32 u[2]; s16x4 s; } bu; bu.u[0] = b0; bu.u[1] = b1;
  return __builtin_amdgcn_mfma_f32_32x32x8bf16_1k(au.s, bu.s, c, 0, 0, 0);
}
#endif

__global__ __launch_bounds__(512, 4) void attn_kernel(
    const bf16* __restrict__ q, const char* __restrict__ kvt,
    bf16* __restrict__ ao) {
  __shared__ __align__(16) char lds[2][2][16384];   // [kvh][buf][tile image]
  __shared__ float Ll[8][32];
  const int t = threadIdx.x;
  const int lane = t & 63, wid = t >> 6;
  const int l31 = lane & 31, lhi1 = lane >> 5;
  const bool lo = (lane < 32);
  const int bid = blockIdx.x;
  const int xcd = bid & 7, rem = bid >> 3;     // XCD-aware swizzle: 4 bh/XCD
  const int bh = (xcd << 2) + (rem >> 4);
  const int q0 = (rem & 15) * 128;
  const int qt = wid >> 1, kvh = wid & 1;

  // Q B-fragments: lane holds q=l31, d = kc*16 + lhi1*8 + j
  bf16x8 qf[4];
  {
    const bf16* qp = q + ((size_t)bh * NN + q0 + qt * 32 + l31) * 64 + lhi1 * 8;
#pragma unroll
    for (int c = 0; c < 4; ++c) qf[c] = *(const bf16x8*)(qp + c * 16);
  }

  // staging: wave DMA-copies quarter qt of its kv-group's tile (4x1KB)
  const char* sp = kvt + ((size_t)(bh * 64 + kvh * 32)) * 16384 + qt * 4096 + lane * 16;
  char* wq[2] = { &lds[kvh][0][qt * 4096], &lds[kvh][1][qt * 4096] };

#define STAGE(BUF)                                                        \
  {                                                                       \
    gload16(sp,        wq[BUF]);                                          \
    gload16(sp + 1024, wq[BUF] + 1024);                                   \
    gload16(sp + 2048, wq[BUF] + 2048);                                   \
    gload16(sp + 3072, wq[BUF] + 3072);                                   \
    sp += 16384;                                                          \
  }

  f32x16 O0a = {}, O0b = {}, O1a = {}, O1b = {}, psum = {};

  STAGE(0);
  __syncthreads();
  int buf = 0;

  for (int kt = 0; kt < 32; ++kt) {
    if (kt + 1 < 32) STAGE(buf ^ 1);
    const char* KB = &lds[kvh][buf][0];
    const char* VB = &lds[kvh][buf][8192];

    // ---- S^T: mfma(A=K rows, B=Q); contiguous 1KB frag reads ----
    f32x16 s0 = {}, s1 = {};
    __builtin_amdgcn_s_setprio(1);
#pragma unroll
    for (int kc = 0; kc < 4; ++kc) {
      bf16x8 k0 = *(const bf16x8*)(KB + ((2 * kc + lhi1) << 9) + l31 * 16);
      bf16x8 k1 = *(const bf16x8*)(KB + 4096 + ((2 * kc + lhi1) << 9) + l31 * 16);
      s0 = __builtin_amdgcn_mfma_f32_32x32x16_bf16(k0, qf[kc], s0, 0, 0, 0);
      s1 = __builtin_amdgcn_mfma_f32_32x32x16_bf16(k1, qf[kc], s1, 0, 0, 0);
    }
    __builtin_amdgcn_s_setprio(0);

    // ---- P = exp2(S) (fixed max), deferred l-sum ----
#pragma unroll
    for (int r = 0; r < 16; ++r) {
      s0[r] = exp2f(s0[r]);
      s1[r] = exp2f(s1[r]);
    }
    psum += s0 + s1;

    // ---- pack P to bf16 words: w(s,rr) = P[kv=8s+4lhi1+2rr+{0,1}][q] ----
    u32 w0[8], w1[8];
#pragma unroll
    for (int s = 0; s < 4; ++s)
#pragma unroll
      for (int rr = 0; rr < 2; ++rr) {
        w0[s * 2 + rr] = pkbf(s0[4 * s + 2 * rr], s0[4 * s + 2 * rr + 1]);
        w1[s * 2 + rr] = pkbf(s1[4 * s + 2 * rr], s1[4 * s + 2 * rr + 1]);
      }

    __builtin_amdgcn_s_setprio(1);
#ifdef HAVE_MFMA8
    // ---- PV via 32x32x8, 4 independent accumulator chains ----
#pragma unroll
    for (int kc = 0; kc < 8; ++kc) {
      u32 b0 = (kc < 4) ? w0[2 * kc] : w1[2 * (kc - 4)];
      u32 b1 = (kc < 4) ? w0[2 * kc + 1] : w1[2 * (kc - 4) + 1];
      bf16x4 a0 = *(const bf16x4*)(VB + (kc << 9) + (lhi1 << 8) + l31 * 8);
      bf16x4 a1 = *(const bf16x4*)(VB + 4096 + (kc << 9) + (lhi1 << 8) + l31 * 8);
      if (kc & 1) { O0b = mfma8(a0, b0, b1, O0b); O1b = mfma8(a1, b0, b1, O1b); }
      else        { O0a = mfma8(a0, b0, b1, O0a); O1a = mfma8(a1, b0, b1, O1a); }
    }
#else
    // ---- PV via 32x32x16 with half-swap exchange (fallback) ----
#pragma unroll
    for (int t2 = 0; t2 < 2; ++t2) {
#pragma unroll
      for (int c2 = 0; c2 < 2; ++c2) {
        u32 aw0 = t2 ? w1[4 * c2 + 0] : w0[4 * c2 + 0];
        u32 aw1 = t2 ? w1[4 * c2 + 1] : w0[4 * c2 + 1];
        u32 bw0 = t2 ? w1[4 * c2 + 2] : w0[4 * c2 + 2];
        u32 bw1 = t2 ? w1[4 * c2 + 3] : w0[4 * c2 + 3];
        u32 xb0 = __shfl_xor(bw0, 32), xb1 = __shfl_xor(bw1, 32);
        u32 xa0 = __shfl_xor(aw0, 32), xa1 = __shfl_xor(aw1, 32);
        union { u32 u[4]; bf16x8 v; } pb;
        pb.u[0] = lo ? aw0 : xb0;
        pb.u[1] = lo ? aw1 : xb1;
        pb.u[2] = lo ? xa0 : bw0;
        pb.u[3] = lo ? xa1 : bw1;
        const int kc = t2 * 2 + c2;
        union { bf16x4 h[2]; bf16x8 v; } va, vb;
        int base = ((2 * kc + lhi1) << 9) + l31 * 8;
        va.h[0] = *(const bf16x4*)(VB + base);
        va.h[1] = *(const bf16x4*)(VB + base + 256);
        vb.h[0] = *(const bf16x4*)(VB + 4096 + base);
        vb.h[1] = *(const bf16x4*)(VB + 4096 + base + 256);
        O0a = __builtin_amdgcn_mfma_f32_32x32x16_bf16(va.v, pb.v, O0a, 0, 0, 0);
        O1a = __builtin_amdgcn_mfma_f32_32x32x16_bf16(vb.v, pb.v, O1a, 0, 0, 0);
      }
    }
#endif
    __builtin_amdgcn_s_setprio(0);

    __syncthreads();   // drains vmcnt(0): DMA for buf^1 landed; all done reading buf
    buf ^= 1;
  }

  f32x16 O0 = O0a + O0b, O1 = O1a + O1b;

  // ---- l = horizontal sum of psum (once) ----
  f32x8 v8 = __builtin_shufflevector(psum, psum, 0, 1, 2, 3, 4, 5, 6, 7) +
             __builtin_shufflevector(psum, psum, 8, 9, 10, 11, 12, 13, 14, 15);
  f32x4 v4 = __builtin_shufflevector(v8, v8, 0, 1, 2, 3) +
             __builtin_shufflevector(v8, v8, 4, 5, 6, 7);
  float ss = (v4[0] + v4[1]) + (v4[2] + v4[3]);
  float l = ss + __shfl_xor(ss, 32);

  // ---- merge the two kv-halves of each q-tile via LDS (pure add) ----
  float* Olf = (float*)&lds[0][0][0];          // [8][64][32] f32 = 64KB
#pragma unroll
  for (int t2 = 0; t2 < 2; ++t2)
#pragma unroll
    for (int r = 0; r < 16; ++r) {
      int d = t2 * 32 + (r & 3) + 8 * (r >> 2) + 4 * lhi1;
      Olf[wid * 2048 + d * 32 + l31] = t2 ? O1[r] : O0[r];
    }
  if (lo) Ll[wid][l31] = l;
  __syncthreads();

  const int pw = wid ^ 1;
  float inv = 1.f / (l + Ll[pw][l31]);
  const int dth = kvh;
  f32x16 Os = dth ? O1 : O0;
  bf16* op = ao + ((size_t)bh * NN + q0 + qt * 32 + l31) * 64 + dth * 32 + 4 * lhi1;
#pragma unroll
  for (int rg = 0; rg < 4; ++rg) {
    bf16x4 ov;
#pragma unroll
    for (int e = 0; e < 4; ++e) {
      int r = rg * 4 + e;
      int d = dth * 32 + e + 8 * rg + 4 * lhi1;
      float comb = Os[r] + Olf[pw * 2048 + d * 32 + l31];
      ov[e] = (bf16)(comb * inv);
    }
    *(bf16x4*)(op + 8 * rg) = ov;
  }
#undef STAGE
}

// ---------------------------------------------------------------------------
extern "C" void kernel_launch(void* const* d_in, const int* in_sizes, int n_in,
                              void* d_out, int out_size, void* d_ws, size_t ws_size,
                              hipStream_t stream) {
  const float* nuc = (const float*)d_in[0];
  const float* ele = (const float*)d_in[1];
  const float* Wq  = (const float*)d_in[2];
  const float* bq  = (const float*)d_in[3];
  const float* Wk  = (const float*)d_in[4];
  const float* bk  = (const float*)d_in[5];
  const float* Wv  = (const float*)d_in[6];
  const float* bv  = (const float*)d_in[7];
  const float* Wo  = (const float*)d_in[8];
  const float* bo  = (const float*)d_in[9];
  float* out = (float*)d_out;
  char* ws = (char*)d_ws;

  bf16* wtq  = (bf16*)(ws + 0);
  bf16* wtkv = (bf16*)(ws + 131072);     // wtk / wtv adjacent
  bf16* wtk  = (bf16*)(ws + 131072);
  bf16* wtv  = (bf16*)(ws + 262144);
  bf16* wto  = (bf16*)(ws + 393216);
  bf16* qhs  = (bf16*)(ws + 524288);     // [32][2048][64] bf16, 8MB
  char* kvt  = (char*)(ws + 8912896);    // [32][64][16KB] K/V images, 32MB
  bf16* aoh  = (bf16*)(ws + 42467328);   // [32][2048][64] bf16, 8MB

  prep_wt<<<dim3(256, 4), 256, 0, stream>>>(Wq, Wk, Wv, Wo, wtq, wtk, wtv, wto);

  // Q scaled by 1/sqrt(64) * log2(e)  (softmax computed in exp2 domain)
  gemm_bias<0, 1><<<dim3(128, 2), 256, 0, stream>>>(nuc, wtq, bq, nullptr, qhs, 0.18033688011112042f);
  // fused K+V projection: Wt = [512][256], cols 0-255 -> K image, 256-511 -> V image
  gemm_bias<0, 4><<<dim3(256, 4), 256, 0, stream>>>(ele, wtkv, bk, bv, kvt, 1.0f);

  attn_kernel<<<dim3(512), 512, 0, stream>>>(qhs, kvt, aoh);

  gemm_bias<1, 0><<<dim3(128, 2), 256, 0, stream>>>(aoh, wto, bo, nullptr, out, 1.0f);
}

// Round 9
// 172.026 us; speedup vs baseline: 1.7213x; 1.7213x over previous
//
#include <hip/hip_runtime.h>

typedef __bf16 bf16;
typedef bf16 bf16x8 __attribute__((ext_vector_type(8)));
typedef bf16 bf16x4 __attribute__((ext_vector_type(4)));
typedef float f32x4 __attribute__((ext_vector_type(4)));
typedef float f32x8 __attribute__((ext_vector_type(8)));
typedef float f32x16 __attribute__((ext_vector_type(16)));
typedef unsigned int u32;

#define BB 8
#define NN 2048
#define MM 4096

// ---------------------------------------------------------------------------
// Weight prep: W[k][n] f32 -> Wt[n][k] bf16  (4 matrices in one launch)
// ---------------------------------------------------------------------------
__global__ __launch_bounds__(256) void prep_wt(
    const float* W0, const float* W1, const float* W2, const float* W3,
    bf16* T0, bf16* T1, bf16* T2, bf16* T3) {
  const float* W; bf16* T;
  switch (blockIdx.y) {
    case 0:  W = W0; T = T0; break;
    case 1:  W = W1; T = T1; break;
    case 2:  W = W2; T = T2; break;
    default: W = W3; T = T3; break;
  }
  int n = blockIdx.x, k = threadIdx.x;
  T[n * 256 + k] = (bf16)W[k * 256 + n];
}

// ---------------------------------------------------------------------------
// GEMM: C = (A[R][256] @ W + bias) * scale, W as Wt[n][k] bf16.
// AM: 0 = A f32 flat [R][256]; 1 = A bf16 head-split [b*4+h][2048][64]
// CM: 0 = C f32 flat; 1 = C bf16 head-split;
//     4 = fused K/V image write via LDS-staged coalesced epilogue
// ---------------------------------------------------------------------------
template<int AM, int CM>
__global__ __launch_bounds__(256) void gemm_bias(
    const void* Aptr, const bf16* Wt, const float* bias, const float* bias2,
    void* Cout, float scale) {
  __shared__ __align__(16) char smem[32768];
  bf16* As = (bf16*)smem;
  bf16* Bs = (bf16*)(smem + 16384);
  const int t = threadIdx.x;
  const int lane = t & 63, wid = t >> 6;
  const int l15 = lane & 15, lhi = lane >> 4, l7 = lane & 7;
  const int row0 = blockIdx.x * 128, col0 = blockIdx.y * 128;
  const int wm = (wid >> 1) * 64, wn = (wid & 1) * 64;

  f32x4 zero4 = {0.f, 0.f, 0.f, 0.f};
  f32x4 acc[4][4];
#pragma unroll
  for (int i = 0; i < 4; ++i)
#pragma unroll
    for (int j = 0; j < 4; ++j) acc[i][j] = zero4;

  for (int k0 = 0; k0 < 256; k0 += 64) {
    __syncthreads();
    if (AM == 0) {
      const float* Af = (const float*)Aptr;
#pragma unroll
      for (int i = 0; i < 8; ++i) {
        int idx = t + i * 256;
        int m = idx >> 4, c4 = idx & 15;
        f32x4 v = *(const f32x4*)(Af + (size_t)(row0 + m) * 256 + k0 + c4 * 4);
        bf16x4 bv;
#pragma unroll
        for (int j = 0; j < 4; ++j) bv[j] = (bf16)v[j];
        *(bf16x4*)((char*)As + m * 128 + ((c4 * 8) ^ ((m & 7) << 4))) = bv;
      }
    } else {
      const bf16* Ab = (const bf16*)Aptr;
#pragma unroll
      for (int i = 0; i < 4; ++i) {
        int idx = t + i * 256;
        int m = idx >> 3, c = idx & 7;
        int r = row0 + m;
        int b = r >> 11, nl = r & 2047, h = k0 >> 6;
        const bf16* src = Ab + ((size_t)(b * 4 + h) * 2048 + nl) * 64 + c * 8;
        bf16x8 v = *(const bf16x8*)src;
        *(bf16x8*)((char*)As + m * 128 + ((c * 16) ^ ((m & 7) << 4))) = v;
      }
    }
#pragma unroll
    for (int i = 0; i < 4; ++i) {
      int idx = t + i * 256;
      int n = idx >> 3, c = idx & 7;
      bf16x8 v = *(const bf16x8*)(Wt + (size_t)(col0 + n) * 256 + k0 + c * 8);
      *(bf16x8*)((char*)Bs + n * 128 + ((c * 16) ^ ((n & 7) << 4))) = v;
    }
    __syncthreads();
#pragma unroll
    for (int kh = 0; kh < 2; ++kh) {
      bf16x8 a[4], b[4];
#pragma unroll
      for (int mi = 0; mi < 4; ++mi) {
        int row = wm + mi * 16 + l15;
        a[mi] = *(const bf16x8*)((char*)As + row * 128 + ((kh * 64 + lhi * 16) ^ (l7 << 4)));
      }
#pragma unroll
      for (int ni = 0; ni < 4; ++ni) {
        int row = wn + ni * 16 + l15;
        b[ni] = *(const bf16x8*)((char*)Bs + row * 128 + ((kh * 64 + lhi * 16) ^ (l7 << 4)));
      }
#pragma unroll
      for (int mi = 0; mi < 4; ++mi)
#pragma unroll
        for (int ni = 0; ni < 4; ++ni)
          acc[mi][ni] = __builtin_amdgcn_mfma_f32_16x16x32_bf16(a[mi], b[ni], acc[mi][ni], 0, 0, 0);
    }
  }

  if (CM == 4) __syncthreads();   // done with As/Bs; reuse smem as image stage

#pragma unroll
  for (int mi = 0; mi < 4; ++mi)
#pragma unroll
    for (int ni = 0; ni < 4; ++ni) {
      int n = col0 + wn + ni * 16 + l15;
      float bvv = (CM == 4) ? (n < 256 ? bias[n] : bias2[n - 256]) : bias[n];
#pragma unroll
      for (int r = 0; r < 4; ++r) {
        int mrow = row0 + wm + mi * 16 + lhi * 4 + r;
        float val = (acc[mi][ni][r] + bvv) * scale;
        if (CM == 0) {
          ((float*)Cout)[(size_t)mrow * 256 + n] = val;
        } else if (CM == 1) {
          int b = mrow >> 11, nl = mrow & 2047;
          ((bf16*)Cout)[((size_t)(b * 4 + (n >> 6)) * 2048 + nl) * 64 + (n & 63)] = (bf16)val;
        } else {
          // CM==4: write exact image bytes into LDS (coalesced copy after)
          int dm = wm + mi * 16 + lhi * 4 + r;     // 0..127
          int dn = wn + ni * 16 + l15;             // 0..127
          int dkt = dm >> 6, kvl = dm & 63;
          int dh = dn >> 6, d = dn & 63;
          int inner;
          if (col0 < 256)  // K image: [kv>>5][d>>3][kv&31][d&7]
            inner = (((kvl >> 5) & 1) << 12) + ((d >> 3) << 9)
                  + ((kvl & 31) << 4) + ((d & 7) << 1);
          else             // V image: [d>>5][(kv>>3)&7][(kv>>2)&1][d&31][kv&3]
            inner = ((d >> 5) << 12) + (((kvl >> 3) & 7) << 9)
                  + (((kvl >> 2) & 1) << 8) + ((d & 31) << 3) + ((kvl & 3) << 1);
          *(bf16*)(smem + (dkt * 2 + dh) * 8192 + inner) = (bf16)val;
        }
      }
    }

  if (CM == 4) {
    __syncthreads();
    const int isK = (col0 < 256);
    int b = row0 >> 12, kt0 = (row0 & 4095) >> 6, h0 = (col0 & 255) >> 6;
#pragma unroll
    for (int c = 0; c < 4; ++c) {
      int dkt = c >> 1, dh = c & 1;
      char* dst = (char*)Cout + ((size_t)((b * 4 + h0 + dh) * 64 + kt0 + dkt)) * 16384
                  + (isK ? 0 : 8192);
      *(bf16x8*)(dst + t * 16)        = *(const bf16x8*)(smem + c * 8192 + t * 16);
      *(bf16x8*)(dst + 4096 + t * 16) = *(const bf16x8*)(smem + c * 8192 + 4096 + t * 16);
    }
  }
}

// ---------------------------------------------------------------------------
// Flash cross-attention, swapped-operand, LDS-image K/V tiles, kv-split x2.
// Block = 128 q x (b,h), 8 waves: wave w -> q-tile (w>>1), kv-half (w&1).
// Fixed-max softmax (exp2 domain). Register staging (L2/L3-reuse friendly;
// gload_lds DMA measured 33x HBM overfetch here - round 8). PV accumulators
// split into 4 independent chains (dep-latency relief).
// ---------------------------------------------------------------------------
__device__ __forceinline__ u32 pkbf(float a, float b) {
  union { bf16 h[2]; u32 u; } p;
  p.h[0] = (bf16)a; p.h[1] = (bf16)b;
  return p.u;
}

#if defined(__has_builtin)
#if __has_builtin(__builtin_amdgcn_mfma_f32_32x32x8bf16_1k)
#define HAVE_MFMA8 1
#endif
#endif

#ifdef HAVE_MFMA8
typedef short s16x4 __attribute__((ext_vector_type(4)));
__device__ __forceinline__ f32x16 mfma8(bf16x4 a, u32 b0, u32 b1, f32x16 c) {
  union { bf16x4 h; s16x4 s; } au; au.h = a;
  union { u32 u[2]; s16x4 s; } bu; bu.u[0] = b0; bu.u[1] = b1;
  return __builtin_amdgcn_mfma_f32_32x32x8bf16_1k(au.s, bu.s, c, 0, 0, 0);
}
#endif

__global__ __launch_bounds__(512) void attn_kernel(
    const bf16* __restrict__ q, const char* __restrict__ kvt,
    bf16* __restrict__ ao) {
  __shared__ __align__(16) char lds[2][2][16384];   // [kvh][buf][tile image]
  __shared__ float Ll[8][32];
  const int t = threadIdx.x;
  const int lane = t & 63, wid = t >> 6;
  const int l31 = lane & 31, lhi1 = lane >> 5;
  const bool lo = (lane < 32);
  const int bid = blockIdx.x;
  const int xcd = bid & 7, rem = bid >> 3;     // XCD-aware swizzle: 4 bh/XCD
  const int bh = (xcd << 2) + (rem >> 4);
  const int q0 = (rem & 15) * 128;
  const int qt = wid >> 1, kvh = wid & 1;

  // Q B-fragments: lane holds q=l31, d = kc*16 + lhi1*8 + j
  bf16x8 qf[4];
  {
    const bf16* qp = q + ((size_t)bh * NN + q0 + qt * 32 + l31) * 64 + lhi1 * 8;
#pragma unroll
    for (int c = 0; c < 4; ++c) qf[c] = *(const bf16x8*)(qp + c * 16);
  }

  // staging: wave stages quarter qt of its kv-group's tile (4KB = 4x16B/lane)
  const char* sp = kvt + ((size_t)(bh * 64 + kvh * 32)) * 16384 + qt * 4096 + lane * 16;
  char* wp0 = &lds[kvh][0][qt * 4096 + lane * 16];
  char* wp1 = &lds[kvh][1][qt * 4096 + lane * 16];

  f32x16 O0a = {}, O0b = {}, O1a = {}, O1b = {}, psum = {};

  bf16x8 st0, st1, st2, st3;
#define SLOAD()                                                           \
  {                                                                       \
    st0 = *(const bf16x8*)(sp);                                           \
    st1 = *(const bf16x8*)(sp + 1024);                                    \
    st2 = *(const bf16x8*)(sp + 2048);                                    \
    st3 = *(const bf16x8*)(sp + 3072);                                    \
    sp += 16384;                                                          \
  }
#define SWRITE(WP)                                                        \
  {                                                                       \
    *(bf16x8*)(WP) = st0;                                                 \
    *(bf16x8*)((WP) + 1024) = st1;                                        \
    *(bf16x8*)((WP) + 2048) = st2;                                        \
    *(bf16x8*)((WP) + 3072) = st3;                                        \
  }

  SLOAD(); SWRITE(wp0);
  __syncthreads();
  int buf = 0;

  for (int kt = 0; kt < 32; ++kt) {
    if (kt + 1 < 32) SLOAD();
    const char* KB = &lds[kvh][buf][0];
    const char* VB = &lds[kvh][buf][8192];

    // ---- S^T: mfma(A=K rows, B=Q); contiguous 1KB frag reads ----
    f32x16 s0 = {}, s1 = {};
    __builtin_amdgcn_s_setprio(1);
#pragma unroll
    for (int kc = 0; kc < 4; ++kc) {
      bf16x8 k0 = *(const bf16x8*)(KB + ((2 * kc + lhi1) << 9) + l31 * 16);
      bf16x8 k1 = *(const bf16x8*)(KB + 4096 + ((2 * kc + lhi1) << 9) + l31 * 16);
      s0 = __builtin_amdgcn_mfma_f32_32x32x16_bf16(k0, qf[kc], s0, 0, 0, 0);
      s1 = __builtin_amdgcn_mfma_f32_32x32x16_bf16(k1, qf[kc], s1, 0, 0, 0);
    }
    __builtin_amdgcn_s_setprio(0);

    // ---- P = exp2(S) (fixed max), deferred l-sum ----
#pragma unroll
    for (int r = 0; r < 16; ++r) {
      s0[r] = exp2f(s0[r]);
      s1[r] = exp2f(s1[r]);
    }
    psum += s0 + s1;

    // ---- pack P to bf16 words: w(s,rr) = P[kv=8s+4lhi1+2rr+{0,1}][q] ----
    u32 w0[8], w1[8];
#pragma unroll
    for (int s = 0; s < 4; ++s)
#pragma unroll
      for (int rr = 0; rr < 2; ++rr) {
        w0[s * 2 + rr] = pkbf(s0[4 * s + 2 * rr], s0[4 * s + 2 * rr + 1]);
        w1[s * 2 + rr] = pkbf(s1[4 * s + 2 * rr], s1[4 * s + 2 * rr + 1]);
      }

    __builtin_amdgcn_s_setprio(1);
#ifdef HAVE_MFMA8
    // ---- PV via 32x32x8, 4 independent accumulator chains ----
#pragma unroll
    for (int kc = 0; kc < 8; ++kc) {
      u32 b0 = (kc < 4) ? w0[2 * kc] : w1[2 * (kc - 4)];
      u32 b1 = (kc < 4) ? w0[2 * kc + 1] : w1[2 * (kc - 4) + 1];
      bf16x4 a0 = *(const bf16x4*)(VB + (kc << 9) + (lhi1 << 8) + l31 * 8);
      bf16x4 a1 = *(const bf16x4*)(VB + 4096 + (kc << 9) + (lhi1 << 8) + l31 * 8);
      if (kc & 1) { O0b = mfma8(a0, b0, b1, O0b); O1b = mfma8(a1, b0, b1, O1b); }
      else        { O0a = mfma8(a0, b0, b1, O0a); O1a = mfma8(a1, b0, b1, O1a); }
    }
#else
    // ---- PV via 32x32x16 with half-swap exchange (fallback) ----
#pragma unroll
    for (int t2 = 0; t2 < 2; ++t2) {
#pragma unroll
      for (int c2 = 0; c2 < 2; ++c2) {
        u32 aw0 = t2 ? w1[4 * c2 + 0] : w0[4 * c2 + 0];
        u32 aw1 = t2 ? w1[4 * c2 + 1] : w0[4 * c2 + 1];
        u32 bw0 = t2 ? w1[4 * c2 + 2] : w0[4 * c2 + 2];
        u32 bw1 = t2 ? w1[4 * c2 + 3] : w0[4 * c2 + 3];
        u32 xb0 = __shfl_xor(bw0, 32), xb1 = __shfl_xor(bw1, 32);
        u32 xa0 = __shfl_xor(aw0, 32), xa1 = __shfl_xor(aw1, 32);
        union { u32 u[4]; bf16x8 v; } pb;
        pb.u[0] = lo ? aw0 : xb0;
        pb.u[1] = lo ? aw1 : xb1;
        pb.u[2] = lo ? xa0 : bw0;
        pb.u[3] = lo ? xa1 : bw1;
        const int kc = t2 * 2 + c2;
        union { bf16x4 h[2]; bf16x8 v; } va, vb;
        int base = ((2 * kc + lhi1) << 9) + l31 * 8;
        va.h[0] = *(const bf16x4*)(VB + base);
        va.h[1] = *(const bf16x4*)(VB + base + 256);
        vb.h[0] = *(const bf16x4*)(VB + 4096 + base);
        vb.h[1] = *(const bf16x4*)(VB + 4096 + base + 256);
        O0a = __builtin_amdgcn_mfma_f32_32x32x16_bf16(va.v, pb.v, O0a, 0, 0, 0);
        O1a = __builtin_amdgcn_mfma_f32_32x32x16_bf16(vb.v, pb.v, O1a, 0, 0, 0);
      }
    }
#endif
    __builtin_amdgcn_s_setprio(0);

    if (kt + 1 < 32) SWRITE(buf ? wp0 : wp1);
    __syncthreads();
    buf ^= 1;
  }

  f32x16 O0 = O0a + O0b, O1 = O1a + O1b;

  // ---- l = horizontal sum of psum (once) ----
  f32x8 v8 = __builtin_shufflevector(psum, psum, 0, 1, 2, 3, 4, 5, 6, 7) +
             __builtin_shufflevector(psum, psum, 8, 9, 10, 11, 12, 13, 14, 15);
  f32x4 v4 = __builtin_shufflevector(v8, v8, 0, 1, 2, 3) +
             __builtin_shufflevector(v8, v8, 4, 5, 6, 7);
  float ss = (v4[0] + v4[1]) + (v4[2] + v4[3]);
  float l = ss + __shfl_xor(ss, 32);

  // ---- merge the two kv-halves of each q-tile via LDS (pure add) ----
  float* Olf = (float*)&lds[0][0][0];          // [8][64][32] f32 = 64KB
#pragma unroll
  for (int t2 = 0; t2 < 2; ++t2)
#pragma unroll
    for (int r = 0; r < 16; ++r) {
      int d = t2 * 32 + (r & 3) + 8 * (r >> 2) + 4 * lhi1;
      Olf[wid * 2048 + d * 32 + l31] = t2 ? O1[r] : O0[r];
    }
  if (lo) Ll[wid][l31] = l;
  __syncthreads();

  const int pw = wid ^ 1;
  float inv = 1.f / (l + Ll[pw][l31]);
  const int dth = kvh;
  f32x16 Os = dth ? O1 : O0;
  bf16* op = ao + ((size_t)bh * NN + q0 + qt * 32 + l31) * 64 + dth * 32 + 4 * lhi1;
#pragma unroll
  for (int rg = 0; rg < 4; ++rg) {
    bf16x4 ov;
#pragma unroll
    for (int e = 0; e < 4; ++e) {
      int r = rg * 4 + e;
      int d = dth * 32 + e + 8 * rg + 4 * lhi1;
      float comb = Os[r] + Olf[pw * 2048 + d * 32 + l31];
      ov[e] = (bf16)(comb * inv);
    }
    *(bf16x4*)(op + 8 * rg) = ov;
  }
#undef SLOAD
#undef SWRITE
}

// ---------------------------------------------------------------------------
extern "C" void kernel_launch(void* const* d_in, const int* in_sizes, int n_in,
                              void* d_out, int out_size, void* d_ws, size_t ws_size,
                              hipStream_t stream) {
  const float* nuc = (const float*)d_in[0];
  const float* ele = (const float*)d_in[1];
  const float* Wq  = (const float*)d_in[2];
  const float* bq  = (const float*)d_in[3];
  const float* Wk  = (const float*)d_in[4];
  const float* bk  = (const float*)d_in[5];
  const float* Wv  = (const float*)d_in[6];
  const float* bv  = (const float*)d_in[7];
  const float* Wo  = (const float*)d_in[8];
  const float* bo  = (const float*)d_in[9];
  float* out = (float*)d_out;
  char* ws = (char*)d_ws;

  bf16* wtq  = (bf16*)(ws + 0);
  bf16* wtkv = (bf16*)(ws + 131072);     // wtk / wtv adjacent
  bf16* wtk  = (bf16*)(ws + 131072);
  bf16* wtv  = (bf16*)(ws + 262144);
  bf16* wto  = (bf16*)(ws + 393216);
  bf16* qhs  = (bf16*)(ws + 524288);     // [32][2048][64] bf16, 8MB
  char* kvt  = (char*)(ws + 8912896);    // [32][64][16KB] K/V images, 32MB
  bf16* aoh  = (bf16*)(ws + 42467328);   // [32][2048][64] bf16, 8MB

  prep_wt<<<dim3(256, 4), 256, 0, stream>>>(Wq, Wk, Wv, Wo, wtq, wtk, wtv, wto);

  // Q scaled by 1/sqrt(64) * log2(e)  (softmax computed in exp2 domain)
  gemm_bias<0, 1><<<dim3(128, 2), 256, 0, stream>>>(nuc, wtq, bq, nullptr, qhs, 0.18033688011112042f);
  // fused K+V projection: Wt = [512][256], cols 0-255 -> K image, 256-511 -> V image
  gemm_bias<0, 4><<<dim3(256, 4), 256, 0, stream>>>(ele, wtkv, bk, bv, kvt, 1.0f);

  attn_kernel<<<dim3(512), 512, 0, stream>>>(qhs, kvt, aoh);

  gemm_bias<1, 0><<<dim3(128, 2), 256, 0, stream>>>(aoh, wto, bo, nullptr, out, 1.0f);
}

// Round 11
// 169.388 us; speedup vs baseline: 1.7481x; 1.0156x over previous
//
#include <hip/hip_runtime.h>

typedef __bf16 bf16;
typedef bf16 bf16x8 __attribute__((ext_vector_type(8)));
typedef bf16 bf16x4 __attribute__((ext_vector_type(4)));
typedef float f32x4 __attribute__((ext_vector_type(4)));
typedef float f32x8 __attribute__((ext_vector_type(8)));
typedef float f32x16 __attribute__((ext_vector_type(16)));
typedef unsigned int u32;

#define BB 8
#define NN 2048
#define MM 4096

// ---------------------------------------------------------------------------
// Weight prep: W[k][n] f32 -> Wt[n][k] bf16  (4 matrices in one launch)
// ---------------------------------------------------------------------------
__global__ __launch_bounds__(256) void prep_wt(
    const float* W0, const float* W1, const float* W2, const float* W3,
    bf16* T0, bf16* T1, bf16* T2, bf16* T3) {
  const float* W; bf16* T;
  switch (blockIdx.y) {
    case 0:  W = W0; T = T0; break;
    case 1:  W = W1; T = T1; break;
    case 2:  W = W2; T = T2; break;
    default: W = W3; T = T3; break;
  }
  int n = blockIdx.x, k = threadIdx.x;
  T[n * 256 + k] = (bf16)W[k * 256 + n];
}

// ---------------------------------------------------------------------------
// GEMM: C = (A[R][256] @ W + bias) * scale, W as Wt[n][k] bf16.
// AM: 0 = A f32 flat [R][256]; 1 = A bf16 head-split [b*4+h][2048][64]
// CM: 0 = C f32 flat; 1 = C bf16 head-split;
//     4 = fused K/V image write via LDS-staged coalesced epilogue
// ---------------------------------------------------------------------------
template<int AM, int CM>
__global__ __launch_bounds__(256) void gemm_bias(
    const void* Aptr, const bf16* Wt, const float* bias, const float* bias2,
    void* Cout, float scale) {
  __shared__ __align__(16) char smem[32768];
  bf16* As = (bf16*)smem;
  bf16* Bs = (bf16*)(smem + 16384);
  const int t = threadIdx.x;
  const int lane = t & 63, wid = t >> 6;
  const int l15 = lane & 15, lhi = lane >> 4, l7 = lane & 7;
  const int row0 = blockIdx.x * 128, col0 = blockIdx.y * 128;
  const int wm = (wid >> 1) * 64, wn = (wid & 1) * 64;

  f32x4 zero4 = {0.f, 0.f, 0.f, 0.f};
  f32x4 acc[4][4];
#pragma unroll
  for (int i = 0; i < 4; ++i)
#pragma unroll
    for (int j = 0; j < 4; ++j) acc[i][j] = zero4;

  for (int k0 = 0; k0 < 256; k0 += 64) {
    __syncthreads();
    if (AM == 0) {
      const float* Af = (const float*)Aptr;
#pragma unroll
      for (int i = 0; i < 8; ++i) {
        int idx = t + i * 256;
        int m = idx >> 4, c4 = idx & 15;
        f32x4 v = *(const f32x4*)(Af + (size_t)(row0 + m) * 256 + k0 + c4 * 4);
        bf16x4 bv;
#pragma unroll
        for (int j = 0; j < 4; ++j) bv[j] = (bf16)v[j];
        *(bf16x4*)((char*)As + m * 128 + ((c4 * 8) ^ ((m & 7) << 4))) = bv;
      }
    } else {
      const bf16* Ab = (const bf16*)Aptr;
#pragma unroll
      for (int i = 0; i < 4; ++i) {
        int idx = t + i * 256;
        int m = idx >> 3, c = idx & 7;
        int r = row0 + m;
        int b = r >> 11, nl = r & 2047, h = k0 >> 6;
        const bf16* src = Ab + ((size_t)(b * 4 + h) * 2048 + nl) * 64 + c * 8;
        bf16x8 v = *(const bf16x8*)src;
        *(bf16x8*)((char*)As + m * 128 + ((c * 16) ^ ((m & 7) << 4))) = v;
      }
    }
#pragma unroll
    for (int i = 0; i < 4; ++i) {
      int idx = t + i * 256;
      int n = idx >> 3, c = idx & 7;
      bf16x8 v = *(const bf16x8*)(Wt + (size_t)(col0 + n) * 256 + k0 + c * 8);
      *(bf16x8*)((char*)Bs + n * 128 + ((c * 16) ^ ((n & 7) << 4))) = v;
    }
    __syncthreads();
#pragma unroll
    for (int kh = 0; kh < 2; ++kh) {
      bf16x8 a[4], b[4];
#pragma unroll
      for (int mi = 0; mi < 4; ++mi) {
        int row = wm + mi * 16 + l15;
        a[mi] = *(const bf16x8*)((char*)As + row * 128 + ((kh * 64 + lhi * 16) ^ (l7 << 4)));
      }
#pragma unroll
      for (int ni = 0; ni < 4; ++ni) {
        int row = wn + ni * 16 + l15;
        b[ni] = *(const bf16x8*)((char*)Bs + row * 128 + ((kh * 64 + lhi * 16) ^ (l7 << 4)));
      }
#pragma unroll
      for (int mi = 0; mi < 4; ++mi)
#pragma unroll
        for (int ni = 0; ni < 4; ++ni)
          acc[mi][ni] = __builtin_amdgcn_mfma_f32_16x16x32_bf16(a[mi], b[ni], acc[mi][ni], 0, 0, 0);
    }
  }

  if (CM == 4) __syncthreads();   // done with As/Bs; reuse smem as image stage

#pragma unroll
  for (int mi = 0; mi < 4; ++mi)
#pragma unroll
    for (int ni = 0; ni < 4; ++ni) {
      int n = col0 + wn + ni * 16 + l15;
      float bvv = (CM == 4) ? (n < 256 ? bias[n] : bias2[n - 256]) : bias[n];
#pragma unroll
      for (int r = 0; r < 4; ++r) {
        int mrow = row0 + wm + mi * 16 + lhi * 4 + r;
        float val = (acc[mi][ni][r] + bvv) * scale;
        if (CM == 0) {
          ((float*)Cout)[(size_t)mrow * 256 + n] = val;
        } else if (CM == 1) {
          int b = mrow >> 11, nl = mrow & 2047;
          ((bf16*)Cout)[((size_t)(b * 4 + (n >> 6)) * 2048 + nl) * 64 + (n & 63)] = (bf16)val;
        } else {
          // CM==4: write exact image bytes into LDS (coalesced copy after)
          int dm = wm + mi * 16 + lhi * 4 + r;     // 0..127
          int dn = wn + ni * 16 + l15;             // 0..127
          int dkt = dm >> 6, kvl = dm & 63;
          int dh = dn >> 6, d = dn & 63;
          int inner;
          if (col0 < 256)  // K image: [kv>>5][d>>3][kv&31][d&7]
            inner = (((kvl >> 5) & 1) << 12) + ((d >> 3) << 9)
                  + ((kvl & 31) << 4) + ((d & 7) << 1);
          else             // V image: [d>>5][(kv>>3)&7][d&31][kv&7]
            inner = ((d >> 5) << 12) + (((kvl >> 3) & 7) << 9)
                  + ((d & 31) << 4) + ((kvl & 7) << 1);
          *(bf16*)(smem + (dkt * 2 + dh) * 8192 + inner) = (bf16)val;
        }
      }
    }

  if (CM == 4) {
    __syncthreads();
    const int isK = (col0 < 256);
    int b = row0 >> 12, kt0 = (row0 & 4095) >> 6, h0 = (col0 & 255) >> 6;
#pragma unroll
    for (int c = 0; c < 4; ++c) {
      int dkt = c >> 1, dh = c & 1;
      char* dst = (char*)Cout + ((size_t)((b * 4 + h0 + dh) * 64 + kt0 + dkt)) * 16384
                  + (isK ? 0 : 8192);
      *(bf16x8*)(dst + t * 16)        = *(const bf16x8*)(smem + c * 8192 + t * 16);
      *(bf16x8*)(dst + 4096 + t * 16) = *(const bf16x8*)(smem + c * 8192 + 4096 + t * 16);
    }
  }
}

// ---------------------------------------------------------------------------
// Flash cross-attention, swapped-operand, LDS-image K/V tiles, kv-split x2.
// Block = 128 q x (b,h), 8 waves: wave w -> q-tile (w>>1), kv-half (w&1).
// Fixed-max softmax (exp2 domain). Register staging (L2/L3-reuse friendly).
// PV via NATIVE 32x32x16 MFMA; B-fragment built with v_permlane32_swap_b32.
// Semantics (disambiguated by round-10 failure): swap(vdst,vsrc) gives
//   vdst' = {vdst.lo, vsrc.lo},  vsrc' = {vdst.hi, vsrc.hi}
// so swap(aw,bw): aw' = pb.u[0] (own-aw/partner-bw), bw' = pb.u[2].
// ---------------------------------------------------------------------------
__device__ __forceinline__ u32 pkbf(float a, float b) {
  union { bf16 h[2]; u32 u; } p;
  p.h[0] = (bf16)a; p.h[1] = (bf16)b;
  return p.u;
}

__global__ __launch_bounds__(512) void attn_kernel(
    const bf16* __restrict__ q, const char* __restrict__ kvt,
    bf16* __restrict__ ao) {
  __shared__ __align__(16) char lds[2][2][16384];   // [kvh][buf][tile image]
  __shared__ float Ll[8][32];
  const int t = threadIdx.x;
  const int lane = t & 63, wid = t >> 6;
  const int l31 = lane & 31, lhi1 = lane >> 5;
  const int bid = blockIdx.x;
  const int xcd = bid & 7, rem = bid >> 3;     // XCD-aware swizzle: 4 bh/XCD
  const int bh = (xcd << 2) + (rem >> 4);
  const int q0 = (rem & 15) * 128;
  const int qt = wid >> 1, kvh = wid & 1;

  // Q B-fragments: lane holds q=l31, d = kc*16 + lhi1*8 + j
  bf16x8 qf[4];
  {
    const bf16* qp = q + ((size_t)bh * NN + q0 + qt * 32 + l31) * 64 + lhi1 * 8;
#pragma unroll
    for (int c = 0; c < 4; ++c) qf[c] = *(const bf16x8*)(qp + c * 16);
  }

  // staging: wave stages quarter qt of its kv-group's tile (4KB = 4x16B/lane)
  const char* sp = kvt + ((size_t)(bh * 64 + kvh * 32)) * 16384 + qt * 4096 + lane * 16;
  char* wp0 = &lds[kvh][0][qt * 4096 + lane * 16];
  char* wp1 = &lds[kvh][1][qt * 4096 + lane * 16];

  f32x16 O0a = {}, O0b = {}, O1a = {}, O1b = {}, psum = {};

  bf16x8 st0, st1, st2, st3;
#define SLOAD()                                                           \
  {                                                                       \
    st0 = *(const bf16x8*)(sp);                                           \
    st1 = *(const bf16x8*)(sp + 1024);                                    \
    st2 = *(const bf16x8*)(sp + 2048);                                    \
    st3 = *(const bf16x8*)(sp + 3072);                                    \
    sp += 16384;                                                          \
  }
#define SWRITE(WP)                                                        \
  {                                                                       \
    *(bf16x8*)(WP) = st0;                                                 \
    *(bf16x8*)((WP) + 1024) = st1;                                        \
    *(bf16x8*)((WP) + 2048) = st2;                                        \
    *(bf16x8*)((WP) + 3072) = st3;                                        \
  }

  SLOAD(); SWRITE(wp0);
  __syncthreads();
  int buf = 0;

  for (int kt = 0; kt < 32; ++kt) {
    if (kt + 1 < 32) SLOAD();
    const char* KB = &lds[kvh][buf][0];
    const char* VB = &lds[kvh][buf][8192];

    // ---- S^T: mfma(A=K rows, B=Q); contiguous 1KB frag reads ----
    f32x16 s0 = {}, s1 = {};
    __builtin_amdgcn_s_setprio(1);
#pragma unroll
    for (int kc = 0; kc < 4; ++kc) {
      bf16x8 k0 = *(const bf16x8*)(KB + ((2 * kc + lhi1) << 9) + l31 * 16);
      bf16x8 k1 = *(const bf16x8*)(KB + 4096 + ((2 * kc + lhi1) << 9) + l31 * 16);
      s0 = __builtin_amdgcn_mfma_f32_32x32x16_bf16(k0, qf[kc], s0, 0, 0, 0);
      s1 = __builtin_amdgcn_mfma_f32_32x32x16_bf16(k1, qf[kc], s1, 0, 0, 0);
    }
    __builtin_amdgcn_s_setprio(0);

    // ---- P = exp2(S) (fixed max), deferred l-sum ----
#pragma unroll
    for (int r = 0; r < 16; ++r) {
      s0[r] = exp2f(s0[r]);
      s1[r] = exp2f(s1[r]);
    }
    psum += s0 + s1;

    // ---- pack P to bf16 words: w(s,rr) = P[kv=8s+4lhi1+2rr+{0,1}][q] ----
    u32 w0[8], w1[8];
#pragma unroll
    for (int s = 0; s < 4; ++s)
#pragma unroll
      for (int rr = 0; rr < 2; ++rr) {
        w0[s * 2 + rr] = pkbf(s0[4 * s + 2 * rr], s0[4 * s + 2 * rr + 1]);
        w1[s * 2 + rr] = pkbf(s1[4 * s + 2 * rr], s1[4 * s + 2 * rr + 1]);
      }

    // ---- PV via native 32x32x16; exchange via v_permlane32_swap_b32 ----
    __builtin_amdgcn_s_setprio(1);
#pragma unroll
    for (int t2 = 0; t2 < 2; ++t2) {
#pragma unroll
      for (int c2 = 0; c2 < 2; ++c2) {
        u32 aw0 = t2 ? w1[4 * c2 + 0] : w0[4 * c2 + 0];
        u32 aw1 = t2 ? w1[4 * c2 + 1] : w0[4 * c2 + 1];
        u32 bw0 = t2 ? w1[4 * c2 + 2] : w0[4 * c2 + 2];
        u32 bw1 = t2 ? w1[4 * c2 + 3] : w0[4 * c2 + 3];
        // swap(vdst=aw, vsrc=bw):
        //   aw' = {aw.lo, bw.lo} -> pb word0 (lanes<32: own aw; >=32: partner bw)
        //   bw' = {aw.hi, bw.hi} -> pb word2 (lanes<32: partner aw; >=32: own bw)
        asm("v_permlane32_swap_b32 %0, %1" : "+v"(aw0), "+v"(bw0));
        asm("v_permlane32_swap_b32 %0, %1" : "+v"(aw1), "+v"(bw1));
        union { u32 u[4]; bf16x8 v; } pb;
        pb.u[0] = aw0;
        pb.u[1] = aw1;
        pb.u[2] = bw0;
        pb.u[3] = bw1;
        const int kb = t2 * 2 + c2;
        int base = ((2 * kb + lhi1) << 9) + l31 * 16;
        bf16x8 va = *(const bf16x8*)(VB + base);
        bf16x8 vb = *(const bf16x8*)(VB + 4096 + base);
        if (kb & 1) {
          O0b = __builtin_amdgcn_mfma_f32_32x32x16_bf16(va, pb.v, O0b, 0, 0, 0);
          O1b = __builtin_amdgcn_mfma_f32_32x32x16_bf16(vb, pb.v, O1b, 0, 0, 0);
        } else {
          O0a = __builtin_amdgcn_mfma_f32_32x32x16_bf16(va, pb.v, O0a, 0, 0, 0);
          O1a = __builtin_amdgcn_mfma_f32_32x32x16_bf16(vb, pb.v, O1a, 0, 0, 0);
        }
      }
    }
    __builtin_amdgcn_s_setprio(0);

    if (kt + 1 < 32) SWRITE(buf ? wp0 : wp1);
    __syncthreads();
    buf ^= 1;
  }

  f32x16 O0 = O0a + O0b, O1 = O1a + O1b;

  // ---- l = horizontal sum of psum (once) ----
  f32x8 v8 = __builtin_shufflevector(psum, psum, 0, 1, 2, 3, 4, 5, 6, 7) +
             __builtin_shufflevector(psum, psum, 8, 9, 10, 11, 12, 13, 14, 15);
  f32x4 v4 = __builtin_shufflevector(v8, v8, 0, 1, 2, 3) +
             __builtin_shufflevector(v8, v8, 4, 5, 6, 7);
  float ss = (v4[0] + v4[1]) + (v4[2] + v4[3]);
  float l = ss + __shfl_xor(ss, 32);

  // ---- merge the two kv-halves of each q-tile via LDS (pure add) ----
  float* Olf = (float*)&lds[0][0][0];          // [8][64][32] f32 = 64KB
#pragma unroll
  for (int t2 = 0; t2 < 2; ++t2)
#pragma unroll
    for (int r = 0; r < 16; ++r) {
      int d = t2 * 32 + (r & 3) + 8 * (r >> 2) + 4 * lhi1;
      Olf[wid * 2048 + d * 32 + l31] = t2 ? O1[r] : O0[r];
    }
  if (lane < 32) Ll[wid][l31] = l;
  __syncthreads();

  const int pw = wid ^ 1;
  float inv = 1.f / (l + Ll[pw][l31]);
  const int dth = kvh;
  f32x16 Os = dth ? O1 : O0;
  bf16* op = ao + ((size_t)bh * NN + q0 + qt * 32 + l31) * 64 + dth * 32 + 4 * lhi1;
#pragma unroll
  for (int rg = 0; rg < 4; ++rg) {
    bf16x4 ov;
#pragma unroll
    for (int e = 0; e < 4; ++e) {
      int r = rg * 4 + e;
      int d = dth * 32 + e + 8 * rg + 4 * lhi1;
      float comb = Os[r] + Olf[pw * 2048 + d * 32 + l31];
      ov[e] = (bf16)(comb * inv);
    }
    *(bf16x4*)(op + 8 * rg) = ov;
  }
#undef SLOAD
#undef SWRITE
}

// ---------------------------------------------------------------------------
extern "C" void kernel_launch(void* const* d_in, const int* in_sizes, int n_in,
                              void* d_out, int out_size, void* d_ws, size_t ws_size,
                              hipStream_t stream) {
  const float* nuc = (const float*)d_in[0];
  const float* ele = (const float*)d_in[1];
  const float* Wq  = (const float*)d_in[2];
  const float* bq  = (const float*)d_in[3];
  const float* Wk  = (const float*)d_in[4];
  const float* bk  = (const float*)d_in[5];
  const float* Wv  = (const float*)d_in[6];
  const float* bv  = (const float*)d_in[7];
  const float* Wo  = (const float*)d_in[8];
  const float* bo  = (const float*)d_in[9];
  float* out = (float*)d_out;
  char* ws = (char*)d_ws;

  bf16* wtq  = (bf16*)(ws + 0);
  bf16* wtkv = (bf16*)(ws + 131072);     // wtk / wtv adjacent
  bf16* wtk  = (bf16*)(ws + 131072);
  bf16* wtv  = (bf16*)(ws + 262144);
  bf16* wto  = (bf16*)(ws + 393216);
  bf16* qhs  = (bf16*)(ws + 524288);     // [32][2048][64] bf16, 8MB
  char* kvt  = (char*)(ws + 8912896);    // [32][64][16KB] K/V images, 32MB
  bf16* aoh  = (bf16*)(ws + 42467328);   // [32][2048][64] bf16, 8MB

  prep_wt<<<dim3(256, 4), 256, 0, stream>>>(Wq, Wk, Wv, Wo, wtq, wtk, wtv, wto);

  // Q scaled by 1/sqrt(64) * log2(e)  (softmax computed in exp2 domain)
  gemm_bias<0, 1><<<dim3(128, 2), 256, 0, stream>>>(nuc, wtq, bq, nullptr, qhs, 0.18033688011112042f);
  // fused K+V projection: Wt = [512][256], cols 0-255 -> K image, 256-511 -> V image
  gemm_bias<0, 4><<<dim3(256, 4), 256, 0, stream>>>(ele, wtkv, bk, bv, kvt, 1.0f);

  attn_kernel<<<dim3(512), 512, 0, stream>>>(qhs, kvt, aoh);

  gemm_bias<1, 0><<<dim3(128, 2), 256, 0, stream>>>(aoh, wto, bo, nullptr, out, 1.0f);
}

// Round 12
// 139.574 us; speedup vs baseline: 2.1215x; 1.2136x over previous
//
#include <hip/hip_runtime.h>

typedef __bf16 bf16;
typedef bf16 bf16x8 __attribute__((ext_vector_type(8)));
typedef bf16 bf16x4 __attribute__((ext_vector_type(4)));
typedef float f32x4 __attribute__((ext_vector_type(4)));
typedef float f32x8 __attribute__((ext_vector_type(8)));
typedef float f32x16 __attribute__((ext_vector_type(16)));
typedef unsigned int u32;

#define BB 8
#define NN 2048
#define MM 4096

#if defined(__has_builtin)
#if __has_builtin(__builtin_amdgcn_exp2f)
#define EXP2(x) __builtin_amdgcn_exp2f(x)
#endif
#endif
#ifndef EXP2
#define EXP2(x) exp2f(x)
#endif

// ---------------------------------------------------------------------------
// Weight prep: W[k][n] f32 -> Wt[n][k] bf16  (4 matrices in one launch)
// ---------------------------------------------------------------------------
__global__ __launch_bounds__(256) void prep_wt(
    const float* W0, const float* W1, const float* W2, const float* W3,
    bf16* T0, bf16* T1, bf16* T2, bf16* T3) {
  const float* W; bf16* T;
  switch (blockIdx.y) {
    case 0:  W = W0; T = T0; break;
    case 1:  W = W1; T = T1; break;
    case 2:  W = W2; T = T2; break;
    default: W = W3; T = T3; break;
  }
  int n = blockIdx.x, k = threadIdx.x;
  T[n * 256 + k] = (bf16)W[k * 256 + n];
}

// ---------------------------------------------------------------------------
// GEMM: C = (A[R][256] @ W + bias) * scale, W as Wt[n][k] bf16.
// AM: 0 = A f32 flat [R][256]; 1 = A bf16 head-split [b*4+h][2048][64]
// CM: 0 = C f32 flat; 1 = C bf16 head-split;
//     4 = fused K/V image write via LDS-staged coalesced epilogue
// ---------------------------------------------------------------------------
template<int AM, int CM>
__global__ __launch_bounds__(256) void gemm_bias(
    const void* Aptr, const bf16* Wt, const float* bias, const float* bias2,
    void* Cout, float scale) {
  __shared__ __align__(16) char smem[32768];
  bf16* As = (bf16*)smem;
  bf16* Bs = (bf16*)(smem + 16384);
  const int t = threadIdx.x;
  const int lane = t & 63, wid = t >> 6;
  const int l15 = lane & 15, lhi = lane >> 4, l7 = lane & 7;
  const int row0 = blockIdx.x * 128, col0 = blockIdx.y * 128;
  const int wm = (wid >> 1) * 64, wn = (wid & 1) * 64;

  f32x4 zero4 = {0.f, 0.f, 0.f, 0.f};
  f32x4 acc[4][4];
#pragma unroll
  for (int i = 0; i < 4; ++i)
#pragma unroll
    for (int j = 0; j < 4; ++j) acc[i][j] = zero4;

  for (int k0 = 0; k0 < 256; k0 += 64) {
    __syncthreads();
    if (AM == 0) {
      const float* Af = (const float*)Aptr;
#pragma unroll
      for (int i = 0; i < 8; ++i) {
        int idx = t + i * 256;
        int m = idx >> 4, c4 = idx & 15;
        f32x4 v = *(const f32x4*)(Af + (size_t)(row0 + m) * 256 + k0 + c4 * 4);
        bf16x4 bv;
#pragma unroll
        for (int j = 0; j < 4; ++j) bv[j] = (bf16)v[j];
        *(bf16x4*)((char*)As + m * 128 + ((c4 * 8) ^ ((m & 7) << 4))) = bv;
      }
    } else {
      const bf16* Ab = (const bf16*)Aptr;
#pragma unroll
      for (int i = 0; i < 4; ++i) {
        int idx = t + i * 256;
        int m = idx >> 3, c = idx & 7;
        int r = row0 + m;
        int b = r >> 11, nl = r & 2047, h = k0 >> 6;
        const bf16* src = Ab + ((size_t)(b * 4 + h) * 2048 + nl) * 64 + c * 8;
        bf16x8 v = *(const bf16x8*)src;
        *(bf16x8*)((char*)As + m * 128 + ((c * 16) ^ ((m & 7) << 4))) = v;
      }
    }
#pragma unroll
    for (int i = 0; i < 4; ++i) {
      int idx = t + i * 256;
      int n = idx >> 3, c = idx & 7;
      bf16x8 v = *(const bf16x8*)(Wt + (size_t)(col0 + n) * 256 + k0 + c * 8);
      *(bf16x8*)((char*)Bs + n * 128 + ((c * 16) ^ ((n & 7) << 4))) = v;
    }
    __syncthreads();
#pragma unroll
    for (int kh = 0; kh < 2; ++kh) {
      bf16x8 a[4], b[4];
#pragma unroll
      for (int mi = 0; mi < 4; ++mi) {
        int row = wm + mi * 16 + l15;
        a[mi] = *(const bf16x8*)((char*)As + row * 128 + ((kh * 64 + lhi * 16) ^ (l7 << 4)));
      }
#pragma unroll
      for (int ni = 0; ni < 4; ++ni) {
        int row = wn + ni * 16 + l15;
        b[ni] = *(const bf16x8*)((char*)Bs + row * 128 + ((kh * 64 + lhi * 16) ^ (l7 << 4)));
      }
#pragma unroll
      for (int mi = 0; mi < 4; ++mi)
#pragma unroll
        for (int ni = 0; ni < 4; ++ni)
          acc[mi][ni] = __builtin_amdgcn_mfma_f32_16x16x32_bf16(a[mi], b[ni], acc[mi][ni], 0, 0, 0);
    }
  }

  if (CM == 4) __syncthreads();   // done with As/Bs; reuse smem as image stage

#pragma unroll
  for (int mi = 0; mi < 4; ++mi)
#pragma unroll
    for (int ni = 0; ni < 4; ++ni) {
      int n = col0 + wn + ni * 16 + l15;
      float bvv = (CM == 4) ? (n < 256 ? bias[n] : bias2[n - 256]) : bias[n];
#pragma unroll
      for (int r = 0; r < 4; ++r) {
        int mrow = row0 + wm + mi * 16 + lhi * 4 + r;
        float val = (acc[mi][ni][r] + bvv) * scale;
        if (CM == 0) {
          ((float*)Cout)[(size_t)mrow * 256 + n] = val;
        } else if (CM == 1) {
          int b = mrow >> 11, nl = mrow & 2047;
          ((bf16*)Cout)[((size_t)(b * 4 + (n >> 6)) * 2048 + nl) * 64 + (n & 63)] = (bf16)val;
        } else {
          // CM==4: write exact image bytes into LDS (coalesced copy after)
          int dm = wm + mi * 16 + lhi * 4 + r;     // 0..127
          int dn = wn + ni * 16 + l15;             // 0..127
          int dkt = dm >> 6, kvl = dm & 63;
          int dh = dn >> 6, d = dn & 63;
          int inner;
          if (col0 < 256)  // K image: [kv>>5][d>>3][kv&31][d&7]
            inner = (((kvl >> 5) & 1) << 12) + ((d >> 3) << 9)
                  + ((kvl & 31) << 4) + ((d & 7) << 1);
          else             // V image: [d>>5][(kv>>3)&7][d&31][kv&7]
            inner = ((d >> 5) << 12) + (((kvl >> 3) & 7) << 9)
                  + ((d & 31) << 4) + ((kvl & 7) << 1);
          *(bf16*)(smem + (dkt * 2 + dh) * 8192 + inner) = (bf16)val;
        }
      }
    }

  if (CM == 4) {
    __syncthreads();
    const int isK = (col0 < 256);
    int b = row0 >> 12, kt0 = (row0 & 4095) >> 6, h0 = (col0 & 255) >> 6;
#pragma unroll
    for (int c = 0; c < 4; ++c) {
      int dkt = c >> 1, dh = c & 1;
      char* dst = (char*)Cout + ((size_t)((b * 4 + h0 + dh) * 64 + kt0 + dkt)) * 16384
                  + (isK ? 0 : 8192);
      *(bf16x8*)(dst + t * 16)        = *(const bf16x8*)(smem + c * 8192 + t * 16);
      *(bf16x8*)(dst + 4096 + t * 16) = *(const bf16x8*)(smem + c * 8192 + 4096 + t * 16);
    }
  }
}

// ---------------------------------------------------------------------------
// Flash cross-attention, swapped-operand, LDS-image K/V tiles, kv-split x2.
// Block = 128 q x (b,h), 8 waves: wave w -> q-tile (w>>1), kv-half (w&1).
// Fixed-max softmax (exp2 domain, raw v_exp_f32). kt-loop unrolled x2 with
// STATIC buffer pointers (no per-iter buf select). Two O accumulators only
// (round-9 4-chain split reverted: proven neutral, cost 32 VGPRs).
// ---------------------------------------------------------------------------
__device__ __forceinline__ u32 pkbf(float a, float b) {
  union { bf16 h[2]; u32 u; } p;
  p.h[0] = (bf16)a; p.h[1] = (bf16)b;
  return p.u;
}

__global__ __launch_bounds__(512) void attn_kernel(
    const bf16* __restrict__ q, const char* __restrict__ kvt,
    bf16* __restrict__ ao) {
  __shared__ __align__(16) char lds[2][2][16384];   // [kvh][buf][tile image]
  __shared__ float Ll[8][32];
  const int t = threadIdx.x;
  const int lane = t & 63, wid = t >> 6;
  const int l31 = lane & 31, lhi1 = lane >> 5;
  const int bid = blockIdx.x;
  const int xcd = bid & 7, rem = bid >> 3;     // XCD-aware swizzle: 4 bh/XCD
  const int bh = (xcd << 2) + (rem >> 4);
  const int q0 = (rem & 15) * 128;
  const int qt = wid >> 1, kvh = wid & 1;

  // Q B-fragments: lane holds q=l31, d = kc*16 + lhi1*8 + j
  bf16x8 qf[4];
  {
    const bf16* qp = q + ((size_t)bh * NN + q0 + qt * 32 + l31) * 64 + lhi1 * 8;
#pragma unroll
    for (int c = 0; c < 4; ++c) qf[c] = *(const bf16x8*)(qp + c * 16);
  }

  // staging: wave stages quarter qt of its kv-group's tile (4KB = 4x16B/lane)
  const char* sp = kvt + ((size_t)(bh * 64 + kvh * 32)) * 16384 + qt * 4096 + lane * 16;
  char* wp0 = &lds[kvh][0][qt * 4096 + lane * 16];
  char* wp1 = &lds[kvh][1][qt * 4096 + lane * 16];
  const char* KB0 = &lds[kvh][0][0];
  const char* KB1 = &lds[kvh][1][0];

  f32x16 O0 = {}, O1 = {}, psum = {};

  bf16x8 st0, st1, st2, st3;
#define SLOAD()                                                           \
  {                                                                       \
    st0 = *(const bf16x8*)(sp);                                           \
    st1 = *(const bf16x8*)(sp + 1024);                                    \
    st2 = *(const bf16x8*)(sp + 2048);                                    \
    st3 = *(const bf16x8*)(sp + 3072);                                    \
    sp += 16384;                                                          \
  }
#define SWRITE(WP)                                                        \
  {                                                                       \
    *(bf16x8*)(WP) = st0;                                                 \
    *(bf16x8*)((WP) + 1024) = st1;                                        \
    *(bf16x8*)((WP) + 2048) = st2;                                        \
    *(bf16x8*)((WP) + 3072) = st3;                                        \
  }

  auto compute = [&](const char* KB) {
    const char* VB = KB + 8192;
    // ---- S^T: mfma(A=K rows, B=Q); contiguous 1KB frag reads ----
    f32x16 s0 = {}, s1 = {};
    __builtin_amdgcn_s_setprio(1);
#pragma unroll
    for (int kc = 0; kc < 4; ++kc) {
      bf16x8 k0 = *(const bf16x8*)(KB + ((2 * kc + lhi1) << 9) + l31 * 16);
      bf16x8 k1 = *(const bf16x8*)(KB + 4096 + ((2 * kc + lhi1) << 9) + l31 * 16);
      s0 = __builtin_amdgcn_mfma_f32_32x32x16_bf16(k0, qf[kc], s0, 0, 0, 0);
      s1 = __builtin_amdgcn_mfma_f32_32x32x16_bf16(k1, qf[kc], s1, 0, 0, 0);
    }
    __builtin_amdgcn_s_setprio(0);

    // ---- P = exp2(S) (fixed max, raw v_exp_f32), deferred l-sum ----
#pragma unroll
    for (int r = 0; r < 16; ++r) {
      s0[r] = EXP2(s0[r]);
      s1[r] = EXP2(s1[r]);
    }
    psum += s0 + s1;

    // ---- pack P to bf16 words: w(s,rr) = P[kv=8s+4lhi1+2rr+{0,1}][q] ----
    u32 w0[8], w1[8];
#pragma unroll
    for (int s = 0; s < 4; ++s)
#pragma unroll
      for (int rr = 0; rr < 2; ++rr) {
        w0[s * 2 + rr] = pkbf(s0[4 * s + 2 * rr], s0[4 * s + 2 * rr + 1]);
        w1[s * 2 + rr] = pkbf(s1[4 * s + 2 * rr], s1[4 * s + 2 * rr + 1]);
      }

    // ---- PV via native 32x32x16; exchange via v_permlane32_swap_b32 ----
    __builtin_amdgcn_s_setprio(1);
#pragma unroll
    for (int t2 = 0; t2 < 2; ++t2) {
#pragma unroll
      for (int c2 = 0; c2 < 2; ++c2) {
        u32 aw0 = t2 ? w1[4 * c2 + 0] : w0[4 * c2 + 0];
        u32 aw1 = t2 ? w1[4 * c2 + 1] : w0[4 * c2 + 1];
        u32 bw0 = t2 ? w1[4 * c2 + 2] : w0[4 * c2 + 2];
        u32 bw1 = t2 ? w1[4 * c2 + 3] : w0[4 * c2 + 3];
        // swap(vdst=aw, vsrc=bw): aw'={aw.lo,bw.lo}=pb.u[0]; bw'={aw.hi,bw.hi}=pb.u[2]
        asm("v_permlane32_swap_b32 %0, %1" : "+v"(aw0), "+v"(bw0));
        asm("v_permlane32_swap_b32 %0, %1" : "+v"(aw1), "+v"(bw1));
        union { u32 u[4]; bf16x8 v; } pb;
        pb.u[0] = aw0;
        pb.u[1] = aw1;
        pb.u[2] = bw0;
        pb.u[3] = bw1;
        const int kb = t2 * 2 + c2;
        int base = ((2 * kb + lhi1) << 9) + l31 * 16;
        bf16x8 va = *(const bf16x8*)(VB + base);
        bf16x8 vb = *(const bf16x8*)(VB + 4096 + base);
        O0 = __builtin_amdgcn_mfma_f32_32x32x16_bf16(va, pb.v, O0, 0, 0, 0);
        O1 = __builtin_amdgcn_mfma_f32_32x32x16_bf16(vb, pb.v, O1, 0, 0, 0);
      }
    }
    __builtin_amdgcn_s_setprio(0);
  };

  // ---- prologue: tile0 -> buf0 ----
  SLOAD(); SWRITE(wp0);
  __syncthreads();

  // ---- main loop, unrolled x2: static buffer pointers ----
  for (int kt = 0; kt < 32; kt += 2) {
    SLOAD();                         // tile kt+1
    compute(KB0);                    // tile kt
    SWRITE(wp1);
    __syncthreads();
    if (kt + 2 < 32) SLOAD();        // tile kt+2
    compute(KB1);                    // tile kt+1
    if (kt + 2 < 32) SWRITE(wp0);
    __syncthreads();
  }

  // ---- l = horizontal sum of psum (once) ----
  f32x8 v8 = __builtin_shufflevector(psum, psum, 0, 1, 2, 3, 4, 5, 6, 7) +
             __builtin_shufflevector(psum, psum, 8, 9, 10, 11, 12, 13, 14, 15);
  f32x4 v4 = __builtin_shufflevector(v8, v8, 0, 1, 2, 3) +
             __builtin_shufflevector(v8, v8, 4, 5, 6, 7);
  float ss = (v4[0] + v4[1]) + (v4[2] + v4[3]);
  float l = ss + __shfl_xor(ss, 32);

  // ---- merge the two kv-halves of each q-tile via LDS (pure add) ----
  float* Olf = (float*)&lds[0][0][0];          // [8][64][32] f32 = 64KB
#pragma unroll
  for (int t2 = 0; t2 < 2; ++t2)
#pragma unroll
    for (int r = 0; r < 16; ++r) {
      int d = t2 * 32 + (r & 3) + 8 * (r >> 2) + 4 * lhi1;
      Olf[wid * 2048 + d * 32 + l31] = t2 ? O1[r] : O0[r];
    }
  if (lane < 32) Ll[wid][l31] = l;
  __syncthreads();

  const int pw = wid ^ 1;
  float inv = 1.f / (l + Ll[pw][l31]);
  const int dth = kvh;
  f32x16 Os = dth ? O1 : O0;
  bf16* op = ao + ((size_t)bh * NN + q0 + qt * 32 + l31) * 64 + dth * 32 + 4 * lhi1;
#pragma unroll
  for (int rg = 0; rg < 4; ++rg) {
    bf16x4 ov;
#pragma unroll
    for (int e = 0; e < 4; ++e) {
      int r = rg * 4 + e;
      int d = dth * 32 + e + 8 * rg + 4 * lhi1;
      float comb = Os[r] + Olf[pw * 2048 + d * 32 + l31];
      ov[e] = (bf16)(comb * inv);
    }
    *(bf16x4*)(op + 8 * rg) = ov;
  }
#undef SLOAD
#undef SWRITE
}

// ---------------------------------------------------------------------------
extern "C" void kernel_launch(void* const* d_in, const int* in_sizes, int n_in,
                              void* d_out, int out_size, void* d_ws, size_t ws_size,
                              hipStream_t stream) {
  const float* nuc = (const float*)d_in[0];
  const float* ele = (const float*)d_in[1];
  const float* Wq  = (const float*)d_in[2];
  const float* bq  = (const float*)d_in[3];
  const float* Wk  = (const float*)d_in[4];
  const float* bk  = (const float*)d_in[5];
  const float* Wv  = (const float*)d_in[6];
  const float* bv  = (const float*)d_in[7];
  const float* Wo  = (const float*)d_in[8];
  const float* bo  = (const float*)d_in[9];
  float* out = (float*)d_out;
  char* ws = (char*)d_ws;

  bf16* wtq  = (bf16*)(ws + 0);
  bf16* wtkv = (bf16*)(ws + 131072);     // wtk / wtv adjacent
  bf16* wtk  = (bf16*)(ws + 131072);
  bf16* wtv  = (bf16*)(ws + 262144);
  bf16* wto  = (bf16*)(ws + 393216);
  bf16* qhs  = (bf16*)(ws + 524288);     // [32][2048][64] bf16, 8MB
  char* kvt  = (char*)(ws + 8912896);    // [32][64][16KB] K/V images, 32MB
  bf16* aoh  = (bf16*)(ws + 42467328);   // [32][2048][64] bf16, 8MB

  prep_wt<<<dim3(256, 4), 256, 0, stream>>>(Wq, Wk, Wv, Wo, wtq, wtk, wtv, wto);

  // Q scaled by 1/sqrt(64) * log2(e)  (softmax computed in exp2 domain)
  gemm_bias<0, 1><<<dim3(128, 2), 256, 0, stream>>>(nuc, wtq, bq, nullptr, qhs, 0.18033688011112042f);
  // fused K+V projection: Wt = [512][256], cols 0-255 -> K image, 256-511 -> V image
  gemm_bias<0, 4><<<dim3(256, 4), 256, 0, stream>>>(ele, wtkv, bk, bv, kvt, 1.0f);

  attn_kernel<<<dim3(512), 512, 0, stream>>>(qhs, kvt, aoh);

  gemm_bias<1, 0><<<dim3(128, 2), 256, 0, stream>>>(aoh, wto, bo, nullptr, out, 1.0f);
}